// Round 1
// baseline (209.325 us; speedup 1.0000x reference)
//
#include <hip/hip_runtime.h>

// Dynamic voxelization: coors[d, i] = valid ? floor((p[i,d]-mn[d])/vs[d]) : -1
// Memory-bound streaming: 128 MB read + 96 MB write, no reuse. Floor ~35 us
// at 6.3 TB/s achievable; harness restore (~130 us/iter) rides on top.
//
// Round-2 structure: 4 points/thread (chunked). Per thread:
//   - 4x independent float4 loads (64 B/lane, one full cache line) -> 4x MLP
//   - 3x int4 NT stores (one dwordx4 per plane vs 12 scalar dwords before)
// Loads are PLAIN (not NT): a lane's 4 loads are quarters of the same 64B
// line; NT eviction between quarters could re-fetch from HBM.
// Numerics must match np reference: fp32 sub, IEEE fp32 div, floorf, trunc
// (reciprocal-multiply risks a validity flip at grid boundary -> absmax 1600).

typedef float fx4 __attribute__((ext_vector_type(4)));
typedef int ix4 __attribute__((ext_vector_type(4)));

#define VS_X 0.05f
#define VS_Y 0.05f
#define VS_Z 0.1f
#define MN_X 0.0f
#define MN_Y -40.0f
#define MN_Z -3.0f
#define GX 1408
#define GY 1600
#define GZ 40

__device__ __forceinline__ void voxel_one(const fx4 p, int& vx, int& vy, int& vz) {
    int cx = (int)floorf((p.x - MN_X) / VS_X);
    int cy = (int)floorf((p.y - MN_Y) / VS_Y);
    int cz = (int)floorf((p.z - MN_Z) / VS_Z);
    bool valid = (cx >= 0) & (cx < GX) & (cy >= 0) & (cy < GY) & (cz >= 0) & (cz < GZ);
    vx = valid ? cx : -1;
    vy = valid ? cy : -1;
    vz = valid ? cz : -1;
}

// Fast path: 4 consecutive points per thread, vector stores per plane.
// Requires n % 4 == 0 for 16B alignment of the plane bases (out+n, out+2n).
__global__ __launch_bounds__(256) void voxelize_kernel4(
    const fx4* __restrict__ points, int* __restrict__ out, int n) {
    int t = blockIdx.x * blockDim.x + threadIdx.x;
    int base = t * 4;
    if (base >= n) return;

    // n % 4 == 0 is guaranteed by the launcher for this kernel, so
    // base + 4 <= n always holds here.
    fx4 p0 = points[base + 0];
    fx4 p1 = points[base + 1];
    fx4 p2 = points[base + 2];
    fx4 p3 = points[base + 3];

    int x0, y0, z0, x1, y1, z1, x2, y2, z2, x3, y3, z3;
    voxel_one(p0, x0, y0, z0);
    voxel_one(p1, x1, y1, z1);
    voxel_one(p2, x2, y2, z2);
    voxel_one(p3, x3, y3, z3);

    ix4 ox = {x0, x1, x2, x3};
    ix4 oy = {y0, y1, y2, y3};
    ix4 oz = {z0, z1, z2, z3};

    __builtin_nontemporal_store(ox, (ix4*)(out + base));
    __builtin_nontemporal_store(oy, (ix4*)(out + n + base));
    __builtin_nontemporal_store(oz, (ix4*)(out + 2 * n + base));
}

// Fallback: 1 point/thread (previous round's structure), any n.
__global__ __launch_bounds__(256) void voxelize_kernel1(
    const fx4* __restrict__ points, int* __restrict__ out, int n) {
    int i = blockIdx.x * blockDim.x + threadIdx.x;
    if (i >= n) return;

    fx4 p = __builtin_nontemporal_load(&points[i]);
    int vx, vy, vz;
    voxel_one(p, vx, vy, vz);

    __builtin_nontemporal_store(vx, &out[i]);
    __builtin_nontemporal_store(vy, &out[n + i]);
    __builtin_nontemporal_store(vz, &out[2 * n + i]);
}

extern "C" void kernel_launch(void* const* d_in, const int* in_sizes, int n_in,
                              void* d_out, int out_size, void* d_ws, size_t ws_size,
                              hipStream_t stream) {
    const fx4* points = (const fx4*)d_in[0];
    int* out = (int*)d_out;
    int n = in_sizes[0] / 4;  // points is (N, 4) flat

    int block = 256;
    if ((n & 3) == 0) {
        int threads = n >> 2;
        int grid = (threads + block - 1) / block;
        voxelize_kernel4<<<grid, block, 0, stream>>>(points, out, n);
    } else {
        int grid = (n + block - 1) / block;
        voxelize_kernel1<<<grid, block, 0, stream>>>(points, out, n);
    }
}

// Round 2
// 198.849 us; speedup vs baseline: 1.0527x; 1.0527x over previous
//
#include <hip/hip_runtime.h>

// Dynamic voxelization: coors[d, i] = valid ? floor((p[i,d]-mn[d])/vs[d]) : -1
// Memory-bound streaming: 128 MB read + 96 MB write, no reuse. Floor ~36 us
// at 6.3 TB/s copy ceiling; two harness restore fills (~151 us) ride on top.
//
// Round-2 post-mortem: 4-consecutive-points/thread made loads stride-64B per
// instruction (64 line requests/instr vs 16) -> kernel ~49 -> ~58 us. REVERTED.
//
// Round-3 structure: block owns 1024 consecutive points; thread t handles
// {t, t+256, t+512, t+768}. Every load instr is lane-contiguous (16 B/lane,
// fully coalesced, whole 64B lines consumed per instr -> NT-load safe) and
// each thread has 4 independent loads in flight (4x MLP vs round-0).
// Stores: scalar dword per plane, lane-contiguous (256 B/wave/instr), NT.
// Numerics must match np reference: fp32 sub, IEEE fp32 div, floorf, trunc
// (reciprocal-multiply risks a validity flip at grid boundary -> absmax 1600).

typedef float fx4 __attribute__((ext_vector_type(4)));

#define VS_X 0.05f
#define VS_Y 0.05f
#define VS_Z 0.1f
#define MN_X 0.0f
#define MN_Y -40.0f
#define MN_Z -3.0f
#define GX 1408
#define GY 1600
#define GZ 40

#define PTS_PER_BLOCK 1024  // 256 threads x 4 points, stride-256 within block

__device__ __forceinline__ void voxel_one(const fx4 p, int& vx, int& vy, int& vz) {
    int cx = (int)floorf((p.x - MN_X) / VS_X);
    int cy = (int)floorf((p.y - MN_Y) / VS_Y);
    int cz = (int)floorf((p.z - MN_Z) / VS_Z);
    bool valid = (cx >= 0) & (cx < GX) & (cy >= 0) & (cy < GY) & (cz >= 0) & (cz < GZ);
    vx = valid ? cx : -1;
    vy = valid ? cy : -1;
    vz = valid ? cz : -1;
}

__global__ __launch_bounds__(256) void voxelize_kernel(
    const fx4* __restrict__ points, int* __restrict__ out, int n) {
    int base = blockIdx.x * PTS_PER_BLOCK + threadIdx.x;

    if (base + 768 < n) {
        // Full block: all 4 strided points in range. 4 independent NT loads.
        fx4 p0 = __builtin_nontemporal_load(&points[base]);
        fx4 p1 = __builtin_nontemporal_load(&points[base + 256]);
        fx4 p2 = __builtin_nontemporal_load(&points[base + 512]);
        fx4 p3 = __builtin_nontemporal_load(&points[base + 768]);

        int x0, y0, z0, x1, y1, z1, x2, y2, z2, x3, y3, z3;
        voxel_one(p0, x0, y0, z0);
        voxel_one(p1, x1, y1, z1);
        voxel_one(p2, x2, y2, z2);
        voxel_one(p3, x3, y3, z3);

        int* ox = out;
        int* oy = out + n;
        int* oz = out + 2 * n;
        __builtin_nontemporal_store(x0, ox + base);
        __builtin_nontemporal_store(x1, ox + base + 256);
        __builtin_nontemporal_store(x2, ox + base + 512);
        __builtin_nontemporal_store(x3, ox + base + 768);
        __builtin_nontemporal_store(y0, oy + base);
        __builtin_nontemporal_store(y1, oy + base + 256);
        __builtin_nontemporal_store(y2, oy + base + 512);
        __builtin_nontemporal_store(y3, oy + base + 768);
        __builtin_nontemporal_store(z0, oz + base);
        __builtin_nontemporal_store(z1, oz + base + 256);
        __builtin_nontemporal_store(z2, oz + base + 512);
        __builtin_nontemporal_store(z3, oz + base + 768);
    } else {
        // Tail block: per-point guard.
        #pragma unroll
        for (int k = 0; k < 4; ++k) {
            int i = base + k * 256;
            if (i < n) {
                fx4 p = __builtin_nontemporal_load(&points[i]);
                int vx, vy, vz;
                voxel_one(p, vx, vy, vz);
                __builtin_nontemporal_store(vx, out + i);
                __builtin_nontemporal_store(vy, out + n + i);
                __builtin_nontemporal_store(vz, out + 2 * n + i);
            }
        }
    }
}

extern "C" void kernel_launch(void* const* d_in, const int* in_sizes, int n_in,
                              void* d_out, int out_size, void* d_ws, size_t ws_size,
                              hipStream_t stream) {
    const fx4* points = (const fx4*)d_in[0];
    int* out = (int*)d_out;
    int n = in_sizes[0] / 4;  // points is (N, 4) flat

    int block = 256;
    int grid = (n + PTS_PER_BLOCK - 1) / PTS_PER_BLOCK;
    voxelize_kernel<<<grid, block, 0, stream>>>(points, out, n);
}